// Round 1
// baseline (488.582 us; speedup 1.0000x reference)
//
#include <hip/hip_runtime.h>
#include <stdint.h>

typedef uint16_t u16;
typedef __bf16 bf16x8 __attribute__((ext_vector_type(8)));
typedef float f32x4 __attribute__((ext_vector_type(4)));

#define NCHUNK 16
#define NTILES 250   // 32000 / 128
#define NROWS  4096  // 2L

__device__ __forceinline__ u16 f2b(float x) {
    uint32_t u = __float_as_uint(x);
    u += 0x7FFF + ((u >> 16) & 1);
    return (u16)(u >> 16);
}
__device__ __forceinline__ float b2f(u16 h) {
    return __uint_as_float(((uint32_t)h) << 16);
}

// fp32 -> bf16 (RNE), 4 elems/thread grid-stride
__global__ void k_convert(const float* __restrict__ src, u16* __restrict__ dst, int n) {
    int i = (blockIdx.x * blockDim.x + threadIdx.x) * 4;
    int stride = gridDim.x * blockDim.x * 4;
    for (; i < n; i += stride) {
        float4 v = *(const float4*)(src + i);
        u16 o[4] = {f2b(v.x), f2b(v.y), f2b(v.z), f2b(v.w)};
        *(uint64_t*)(dst + i) = *(const uint64_t*)o;
    }
}

// span gathers -> bf16 context/phrase matrices [2048][1024]
__global__ void k_gather(const float* __restrict__ hidden, const int* __restrict__ begins,
                         const int* __restrict__ ends, const int* __restrict__ bids,
                         u16* __restrict__ ctx, u16* __restrict__ phr) {
    int l = blockIdx.x;
    int b = begins[l], e = ends[l], bd = bids[l];
    const float* h_bm1 = hidden + ((size_t)(b - 1) * 32 + bd) * 1024;
    const float* h_e   = hidden + ((size_t)e * 32 + bd) * 1024;
    const float* h_b   = hidden + ((size_t)b * 32 + bd) * 1024;
    const float* h_em1 = hidden + ((size_t)(e - 1) * 32 + bd) * 1024;
    for (int d = threadIdx.x; d < 1024; d += blockDim.x) {
        float c = (d < 512) ? h_bm1[d] : h_e[d];
        float p = 0.5f * (h_b[d] + h_em1[d]);
        ctx[(size_t)l * 1024 + d] = f2b(c);
        phr[(size_t)l * 1024 + d] = f2b(p);
    }
}

// feats[z*2048 + m][n] = tanh(A[m] . W[n] + bias[n]),  A:[2048][1024] W:[512][1024]
// grid (32, 4, 2): 64-row x 128-col tiles, K=1024 in BK=32 steps
__global__ __launch_bounds__(256) void k_feats(const u16* __restrict__ ctx, const u16* __restrict__ phr,
        const u16* __restrict__ Wc, const u16* __restrict__ Wp,
        const float* __restrict__ bc, const float* __restrict__ bp,
        u16* __restrict__ feats) {
    __shared__ u16 lA[64 * 32];
    __shared__ u16 lB[128 * 32];
    int z = blockIdx.z;
    const u16* A = z ? phr : ctx;
    const u16* W = z ? Wp : Wc;
    const float* bias = z ? bp : bc;
    int m0 = blockIdx.x * 64;
    int n0 = blockIdx.y * 128;
    int t = threadIdx.x;
    int lane = t & 63, w = t >> 6;
    int lrow = lane & 15, lq = lane >> 4;
    f32x4 zero = {0.f, 0.f, 0.f, 0.f};
    f32x4 acc[8];
    for (int i = 0; i < 8; i++) acc[i] = zero;
    for (int kt = 0; kt < 32; kt++) {
        int k0 = kt * 32;
        __syncthreads();
        {   // stage A: 64x32 -> 256 16B segs, 1/thread
            int row = t >> 2, kseg = (t & 3) * 8;
            *(int4*)&lA[row * 32 + kseg] = *(const int4*)&A[(size_t)(m0 + row) * 1024 + k0 + kseg];
        }
        for (int s = t; s < 512; s += 256) {  // stage B: 128x32 -> 512 segs, 2/thread
            int row = s >> 2, kseg = (s & 3) * 8;
            *(int4*)&lB[row * 32 + kseg] = *(const int4*)&W[(size_t)(n0 + row) * 1024 + k0 + kseg];
        }
        __syncthreads();
        bf16x8 af = *(bf16x8*)&lA[(w * 16 + lrow) * 32 + lq * 8];
        for (int ns = 0; ns < 8; ns++) {
            bf16x8 bfr = *(bf16x8*)&lB[(ns * 16 + lrow) * 32 + lq * 8];
            acc[ns] = __builtin_amdgcn_mfma_f32_16x16x32_bf16(af, bfr, acc[ns], 0, 0, 0);
        }
    }
    int zbase = z * 2048;
    for (int ns = 0; ns < 8; ns++) {
        int col = n0 + ns * 16 + lrow;
        float bv = bias[col];
        for (int r = 0; r < 4; r++) {
            int row = zbase + m0 + w * 16 + lq * 4 + r;
            feats[(size_t)row * 512 + col] = f2b(tanhf(acc[ns][r] + bv));
        }
    }
}

// big GEMM + online row-max/sumexp: feats[4096][512] @ Wo_b[32000][512]^T
// grid (32 m-tiles, 16 col-chunks); block 256 = 4 waves, each wave 32 rows x 128 cols
__global__ __launch_bounds__(256) void k_lse(const u16* __restrict__ feats, const u16* __restrict__ Wo,
        float* __restrict__ pm, float* __restrict__ ps) {
    __shared__ u16 lA[128 * 32];
    __shared__ u16 lB[128 * 32];
    int bm = blockIdx.x;
    int chunk = blockIdx.y;
    int t0 = (NTILES * chunk) / NCHUNK;
    int t1 = (NTILES * (chunk + 1)) / NCHUNK;
    int m0 = bm * 128;
    int t = threadIdx.x;
    int lane = t & 63, w = t >> 6;
    int lrow = lane & 15, lq = lane >> 4;
    f32x4 zero = {0.f, 0.f, 0.f, 0.f};
    float m_run[2][4], s_run[2][4];
    for (int ms = 0; ms < 2; ms++)
        for (int r = 0; r < 4; r++) { m_run[ms][r] = -3.0e38f; s_run[ms][r] = 0.f; }

    for (int tile = t0; tile < t1; tile++) {
        int n0 = tile * 128;
        f32x4 acc[2][8];
        for (int ms = 0; ms < 2; ms++)
            for (int ns = 0; ns < 8; ns++) acc[ms][ns] = zero;
        for (int kt = 0; kt < 16; kt++) {
            int k0 = kt * 32;
            __syncthreads();
            for (int s = t; s < 512; s += 256) {
                int row = s >> 2, kseg = (s & 3) * 8;
                *(int4*)&lA[row * 32 + kseg] = *(const int4*)&feats[(size_t)(m0 + row) * 512 + k0 + kseg];
                *(int4*)&lB[row * 32 + kseg] = *(const int4*)&Wo[(size_t)(n0 + row) * 512 + k0 + kseg];
            }
            __syncthreads();
            bf16x8 af0 = *(bf16x8*)&lA[(w * 32 + lrow) * 32 + lq * 8];
            bf16x8 af1 = *(bf16x8*)&lA[(w * 32 + 16 + lrow) * 32 + lq * 8];
            for (int ns = 0; ns < 8; ns++) {
                bf16x8 bfr = *(bf16x8*)&lB[(ns * 16 + lrow) * 32 + lq * 8];
                acc[0][ns] = __builtin_amdgcn_mfma_f32_16x16x32_bf16(af0, bfr, acc[0][ns], 0, 0, 0);
                acc[1][ns] = __builtin_amdgcn_mfma_f32_16x16x32_bf16(af1, bfr, acc[1][ns], 0, 0, 0);
            }
        }
        // online update: per lane, 8 rows x 8 col-samples (cols ns*16 + lrow)
        for (int ms = 0; ms < 2; ms++)
        for (int r = 0; r < 4; r++) {
            float tm = acc[ms][0][r];
            for (int ns = 1; ns < 8; ns++) tm = fmaxf(tm, acc[ms][ns][r]);
            float mn = fmaxf(m_run[ms][r], tm);
            float ssum = 0.f;
            for (int ns = 0; ns < 8; ns++) ssum += __expf(acc[ms][ns][r] - mn);
            s_run[ms][r] = s_run[ms][r] * __expf(m_run[ms][r] - mn) + ssum;
            m_run[ms][r] = mn;
        }
    }
    // merge the 16 column-residue partials (lanes of same quad hold same rows)
    for (int ms = 0; ms < 2; ms++)
    for (int r = 0; r < 4; r++) {
        float m = m_run[ms][r], s = s_run[ms][r];
        for (int off = 1; off < 16; off <<= 1) {
            float mo = __shfl_xor(m, off);
            float so = __shfl_xor(s, off);
            float mn = fmaxf(m, mo);
            s = s * __expf(m - mn) + so * __expf(mo - mn);
            m = mn;
        }
        if (lrow == 0) {
            int row = m0 + w * 32 + ms * 16 + lq * 4 + r;
            pm[row * NCHUNK + chunk] = m;
            ps[row * NCHUNK + chunk] = s;
        }
    }
}

// tag logits: one wave per (row, k): dot(feats[row], Wo[tag]) + bo[tag]
__global__ void k_taglog(const u16* __restrict__ feats, const u16* __restrict__ Wo,
        const float* __restrict__ bo, const int* __restrict__ tags, float* __restrict__ tlog) {
    int gw = blockIdx.x * 4 + (threadIdx.x >> 6);
    int lane = threadIdx.x & 63;
    int i = gw >> 1, k = gw & 1;
    int tg = tags[(i & 2047) * 2 + k];
    const u16* fr = feats + (size_t)i * 512 + lane * 8;
    const u16* wr = Wo + (size_t)tg * 512 + lane * 8;
    float s = 0.f;
    for (int j = 0; j < 8; j++) s += b2f(fr[j]) * b2f(wr[j]);
    for (int off = 32; off >= 1; off >>= 1) s += __shfl_down(s, off);
    if (lane == 0) tlog[i * 2 + k] = s + bo[tg];
}

// lse merge across chunks + loss reduction
__global__ void k_final(const float* __restrict__ pm, const float* __restrict__ ps,
        const float* __restrict__ tlog, const int* __restrict__ tags,
        const float* __restrict__ dp, float* __restrict__ out) {
    __shared__ float red[256];
    float acc = 0.f;
    for (int i = threadIdx.x; i < NROWS; i += 256) {
        float M = -3.0e38f;
        for (int j = 0; j < NCHUNK; j++) M = fmaxf(M, pm[i * NCHUNK + j]);
        float S = 0.f;
        for (int j = 0; j < NCHUNK; j++) S += ps[i * NCHUNK + j] * __expf(pm[i * NCHUNK + j] - M);
        float lse = M + logf(S);
        float num = 0.f, den = 0.f;
        for (int k = 0; k < 2; k++) {
            int tg = tags[(i & 2047) * 2 + k];
            float r = 1.0f - dp[tg];
            num += r * (lse - tlog[i * 2 + k]);
            den += r;
        }
        acc += num / den;
    }
    red[threadIdx.x] = acc;
    __syncthreads();
    for (int s = 128; s > 0; s >>= 1) {
        if (threadIdx.x < s) red[threadIdx.x] += red[threadIdx.x + s];
        __syncthreads();
    }
    if (threadIdx.x == 0) out[0] = red[0] / (4096.0f + 1e-5f);
}

extern "C" void kernel_launch(void* const* d_in, const int* in_sizes, int n_in,
                              void* d_out, int out_size, void* d_ws, size_t ws_size,
                              hipStream_t stream) {
    const float* hidden = (const float*)d_in[0];
    const float* Wc     = (const float*)d_in[1];
    const float* bc     = (const float*)d_in[2];
    const float* Wp     = (const float*)d_in[3];
    const float* bp     = (const float*)d_in[4];
    const float* Wo     = (const float*)d_in[5];
    const float* bo     = (const float*)d_in[6];
    const float* dp     = (const float*)d_in[7];
    const int* begins   = (const int*)d_in[8];
    const int* ends     = (const int*)d_in[9];
    const int* bids     = (const int*)d_in[10];
    const int* tags     = (const int*)d_in[11];
    float* out = (float*)d_out;

    // workspace carve (all 16B-aligned): ~48 MB
    u16* Wo_b    = (u16*)d_ws;
    u16* Wc_b    = Wo_b + 16384000;      // 32000*512
    u16* Wp_b    = Wc_b + 524288;        // 512*1024
    u16* ctx_b   = Wp_b + 524288;
    u16* phr_b   = ctx_b + 2097152;      // 2048*1024
    u16* feats_b = phr_b + 2097152;
    float* pm    = (float*)(feats_b + 2097152);  // 4096*512
    float* ps    = pm + NROWS * NCHUNK;
    float* tlog  = ps + NROWS * NCHUNK;

    k_convert<<<2048, 256, 0, stream>>>(Wo, Wo_b, 16384000);
    k_convert<<<256, 256, 0, stream>>>(Wc, Wc_b, 524288);
    k_convert<<<256, 256, 0, stream>>>(Wp, Wp_b, 524288);
    k_gather<<<2048, 256, 0, stream>>>(hidden, begins, ends, bids, ctx_b, phr_b);
    k_feats<<<dim3(32, 4, 2), 256, 0, stream>>>(ctx_b, phr_b, Wc_b, Wp_b, bc, bp, feats_b);
    k_lse<<<dim3(32, NCHUNK), 256, 0, stream>>>(feats_b, Wo_b, pm, ps);
    k_taglog<<<2048, 256, 0, stream>>>(feats_b, Wo_b, bo, tags, tlog);
    k_final<<<1, 256, 0, stream>>>(pm, ps, tlog, tags, dp, out);
}

// Round 2
// 435.748 us; speedup vs baseline: 1.1212x; 1.1212x over previous
//
#include <hip/hip_runtime.h>
#include <stdint.h>

typedef uint16_t u16;
typedef __bf16 bf16x8 __attribute__((ext_vector_type(8)));
typedef float f32x4 __attribute__((ext_vector_type(4)));

#define NCHUNK 32
#define NTILES 250   // 32000 / 128
#define NROWS  4096  // 2L

__device__ __forceinline__ u16 f2b(float x) {
    uint32_t u = __float_as_uint(x);
    u += 0x7FFF + ((u >> 16) & 1);
    return (u16)(u >> 16);
}
__device__ __forceinline__ float b2f(u16 h) {
    return __uint_as_float(((uint32_t)h) << 16);
}

// async global->LDS, 16B per lane. LDS side must be wave-uniform base + lane*16.
__device__ __forceinline__ void cp16(const void* g, void* l) {
    __builtin_amdgcn_global_load_lds(
        (const __attribute__((address_space(1))) uint32_t*)g,
        (__attribute__((address_space(3))) uint32_t*)l, 16, 0, 0);
}

__device__ __forceinline__ float fast_tanh(float x) {
    x = fminf(15.f, fmaxf(-15.f, x));
    float e = __expf(2.f * x);
    return (e - 1.f) / (e + 1.f);
}

// fp32 -> bf16 (RNE), 4 elems/thread grid-stride
__global__ void k_convert(const float* __restrict__ src, u16* __restrict__ dst, int n) {
    int i = (blockIdx.x * blockDim.x + threadIdx.x) * 4;
    int stride = gridDim.x * blockDim.x * 4;
    for (; i < n; i += stride) {
        float4 v = *(const float4*)(src + i);
        u16 o[4] = {f2b(v.x), f2b(v.y), f2b(v.z), f2b(v.w)};
        *(uint64_t*)(dst + i) = *(const uint64_t*)o;
    }
}

// span gathers -> bf16 context/phrase matrices [2048][1024]
__global__ void k_gather(const float* __restrict__ hidden, const int* __restrict__ begins,
                         const int* __restrict__ ends, const int* __restrict__ bids,
                         u16* __restrict__ ctx, u16* __restrict__ phr) {
    int l = blockIdx.x;
    int b = begins[l], e = ends[l], bd = bids[l];
    const float* h_bm1 = hidden + ((size_t)(b - 1) * 32 + bd) * 1024;
    const float* h_e   = hidden + ((size_t)e * 32 + bd) * 1024;
    const float* h_b   = hidden + ((size_t)b * 32 + bd) * 1024;
    const float* h_em1 = hidden + ((size_t)(e - 1) * 32 + bd) * 1024;
    for (int d = threadIdx.x; d < 1024; d += blockDim.x) {
        float c = (d < 512) ? h_bm1[d] : h_e[d];
        float p = 0.5f * (h_b[d] + h_em1[d]);
        ctx[(size_t)l * 1024 + d] = f2b(c);
        phr[(size_t)l * 1024 + d] = f2b(p);
    }
}

// feats[z*2048 + m][n] = tanh(A[m] . W[n] + bias[n]),  A:[2048][1024] W:[512][1024]
// grid (32, 8, 2): 64x64 tiles, K=1024 in BK=32 steps, async LDS staging
__global__ __launch_bounds__(256) void k_feats(const u16* __restrict__ ctx, const u16* __restrict__ phr,
        const u16* __restrict__ Wc, const u16* __restrict__ Wp,
        const float* __restrict__ bc, const float* __restrict__ bp,
        u16* __restrict__ feats) {
    __shared__ u16 lA[64 * 32];
    __shared__ u16 lB[64 * 32];
    int z = blockIdx.z;
    const u16* A = z ? phr : ctx;
    const u16* W = z ? Wp : Wc;
    const float* bias = z ? bp : bc;
    int m0 = blockIdx.x * 64;
    int n0 = blockIdx.y * 64;
    int t = threadIdx.x;
    int lane = t & 63, w = t >> 6;
    int lrow = lane & 15, lq = lane >> 4;
    f32x4 zero = {0.f, 0.f, 0.f, 0.f};
    f32x4 acc[4];
    for (int i = 0; i < 4; i++) acc[i] = zero;
    int row = t >> 2, kseg = (t & 3) * 8;
    for (int kt = 0; kt < 32; kt++) {
        int k0 = kt * 32;
        __syncthreads();
        cp16(&A[(size_t)(m0 + row) * 1024 + k0 + kseg], &lA[t * 8]);
        cp16(&W[(size_t)(n0 + row) * 1024 + k0 + kseg], &lB[t * 8]);
        __syncthreads();
        bf16x8 af = *(bf16x8*)&lA[(w * 16 + lrow) * 32 + lq * 8];
        for (int ns = 0; ns < 4; ns++) {
            bf16x8 bfr = *(bf16x8*)&lB[(ns * 16 + lrow) * 32 + lq * 8];
            acc[ns] = __builtin_amdgcn_mfma_f32_16x16x32_bf16(af, bfr, acc[ns], 0, 0, 0);
        }
    }
    int zbase = z * 2048;
    for (int ns = 0; ns < 4; ns++) {
        int col = n0 + ns * 16 + lrow;
        float bv = bias[col];
        for (int r = 0; r < 4; r++) {
            int orow = zbase + m0 + w * 16 + lq * 4 + r;
            feats[(size_t)orow * 512 + col] = f2b(fast_tanh(acc[ns][r] + bv));
        }
    }
}

// big GEMM + online row-max/sumexp: feats[4096][512] @ Wo_b[32000][512]^T
// grid (32 m-tiles, 32 col-chunks); block 256 = 4 waves, each wave 32 rows x 128 cols
__global__ __launch_bounds__(256) void k_lse(const u16* __restrict__ feats, const u16* __restrict__ Wo,
        float* __restrict__ pm, float* __restrict__ ps) {
    __shared__ u16 lA[128 * 32];
    __shared__ u16 lB[128 * 32];
    int bm = blockIdx.x;
    int chunk = blockIdx.y;
    int t0 = (NTILES * chunk) / NCHUNK;
    int t1 = (NTILES * (chunk + 1)) / NCHUNK;
    int m0 = bm * 128;
    int t = threadIdx.x;
    int lane = t & 63, w = t >> 6;
    int lrow = lane & 15, lq = lane >> 4;
    f32x4 zero = {0.f, 0.f, 0.f, 0.f};
    float m_run[2][4], s_run[2][4];
    for (int ms = 0; ms < 2; ms++)
        for (int r = 0; r < 4; r++) { m_run[ms][r] = -3.0e38f; s_run[ms][r] = 0.f; }

    int row1 = t >> 2, kseg1 = (t & 3) * 8;          // seg t
    int s2 = t + 256;
    int row2 = s2 >> 2, kseg2 = (s2 & 3) * 8;        // seg t+256

    for (int tile = t0; tile < t1; tile++) {
        int n0 = tile * 128;
        f32x4 acc[2][8];
        for (int ms = 0; ms < 2; ms++)
            for (int ns = 0; ns < 8; ns++) acc[ms][ns] = zero;
        for (int kt = 0; kt < 16; kt++) {
            int k0 = kt * 32;
            __syncthreads();
            cp16(&feats[(size_t)(m0 + row1) * 512 + k0 + kseg1], &lA[t * 8]);
            cp16(&Wo[(size_t)(n0 + row1) * 512 + k0 + kseg1], &lB[t * 8]);
            cp16(&feats[(size_t)(m0 + row2) * 512 + k0 + kseg2], &lA[s2 * 8]);
            cp16(&Wo[(size_t)(n0 + row2) * 512 + k0 + kseg2], &lB[s2 * 8]);
            __syncthreads();
            bf16x8 af0 = *(bf16x8*)&lA[(w * 32 + lrow) * 32 + lq * 8];
            bf16x8 af1 = *(bf16x8*)&lA[(w * 32 + 16 + lrow) * 32 + lq * 8];
            for (int ns = 0; ns < 8; ns++) {
                bf16x8 bfr = *(bf16x8*)&lB[(ns * 16 + lrow) * 32 + lq * 8];
                acc[0][ns] = __builtin_amdgcn_mfma_f32_16x16x32_bf16(af0, bfr, acc[0][ns], 0, 0, 0);
                acc[1][ns] = __builtin_amdgcn_mfma_f32_16x16x32_bf16(af1, bfr, acc[1][ns], 0, 0, 0);
            }
        }
        // online update: per lane, 8 rows x 8 col-samples (cols ns*16 + lrow)
        for (int ms = 0; ms < 2; ms++)
        for (int r = 0; r < 4; r++) {
            float tm = acc[ms][0][r];
            for (int ns = 1; ns < 8; ns++) tm = fmaxf(tm, acc[ms][ns][r]);
            float mn = fmaxf(m_run[ms][r], tm);
            float ssum = 0.f;
            for (int ns = 0; ns < 8; ns++) ssum += __expf(acc[ms][ns][r] - mn);
            s_run[ms][r] = s_run[ms][r] * __expf(m_run[ms][r] - mn) + ssum;
            m_run[ms][r] = mn;
        }
    }
    // merge the 16 column-residue partials (lanes of same quad hold same rows)
    for (int ms = 0; ms < 2; ms++)
    for (int r = 0; r < 4; r++) {
        float m = m_run[ms][r], s = s_run[ms][r];
        for (int off = 1; off < 16; off <<= 1) {
            float mo = __shfl_xor(m, off);
            float so = __shfl_xor(s, off);
            float mn = fmaxf(m, mo);
            s = s * __expf(m - mn) + so * __expf(mo - mn);
            m = mn;
        }
        if (lrow == 0) {
            int row = m0 + w * 32 + ms * 16 + lq * 4 + r;
            pm[row * NCHUNK + chunk] = m;
            ps[row * NCHUNK + chunk] = s;
        }
    }
}

// tag logits: one wave per (row, k): dot(feats[row], Wo[tag]) + bo[tag]
__global__ void k_taglog(const u16* __restrict__ feats, const u16* __restrict__ Wo,
        const float* __restrict__ bo, const int* __restrict__ tags, float* __restrict__ tlog) {
    int gw = blockIdx.x * 4 + (threadIdx.x >> 6);
    int lane = threadIdx.x & 63;
    int i = gw >> 1, k = gw & 1;
    int tg = tags[(i & 2047) * 2 + k];
    union { int4 v; u16 h[8]; } fa, wa;
    fa.v = *(const int4*)(feats + (size_t)i * 512 + lane * 8);
    wa.v = *(const int4*)(Wo + (size_t)tg * 512 + lane * 8);
    float s = 0.f;
    for (int j = 0; j < 8; j++) s += b2f(fa.h[j]) * b2f(wa.h[j]);
    for (int off = 32; off >= 1; off >>= 1) s += __shfl_down(s, off);
    if (lane == 0) tlog[i * 2 + k] = s + bo[tg];
}

// lse merge across chunks + loss reduction
__global__ void k_final(const float* __restrict__ pm, const float* __restrict__ ps,
        const float* __restrict__ tlog, const int* __restrict__ tags,
        const float* __restrict__ dp, float* __restrict__ out) {
    __shared__ float red[256];
    float acc = 0.f;
    for (int i = threadIdx.x; i < NROWS; i += 256) {
        float M = -3.0e38f;
        for (int j = 0; j < NCHUNK; j++) M = fmaxf(M, pm[i * NCHUNK + j]);
        float S = 0.f;
        for (int j = 0; j < NCHUNK; j++) S += ps[i * NCHUNK + j] * __expf(pm[i * NCHUNK + j] - M);
        float lse = M + logf(S);
        float num = 0.f, den = 0.f;
        for (int k = 0; k < 2; k++) {
            int tg = tags[(i & 2047) * 2 + k];
            float r = 1.0f - dp[tg];
            num += r * (lse - tlog[i * 2 + k]);
            den += r;
        }
        acc += num / den;
    }
    red[threadIdx.x] = acc;
    __syncthreads();
    for (int s = 128; s > 0; s >>= 1) {
        if (threadIdx.x < s) red[threadIdx.x] += red[threadIdx.x + s];
        __syncthreads();
    }
    if (threadIdx.x == 0) out[0] = red[0] / (4096.0f + 1e-5f);
}

extern "C" void kernel_launch(void* const* d_in, const int* in_sizes, int n_in,
                              void* d_out, int out_size, void* d_ws, size_t ws_size,
                              hipStream_t stream) {
    const float* hidden = (const float*)d_in[0];
    const float* Wc     = (const float*)d_in[1];
    const float* bc     = (const float*)d_in[2];
    const float* Wp     = (const float*)d_in[3];
    const float* bp     = (const float*)d_in[4];
    const float* Wo     = (const float*)d_in[5];
    const float* bo     = (const float*)d_in[6];
    const float* dp     = (const float*)d_in[7];
    const int* begins   = (const int*)d_in[8];
    const int* ends     = (const int*)d_in[9];
    const int* bids     = (const int*)d_in[10];
    const int* tags     = (const int*)d_in[11];
    float* out = (float*)d_out;

    // workspace carve (all 16B-aligned): ~48 MB
    u16* Wo_b    = (u16*)d_ws;
    u16* Wc_b    = Wo_b + 16384000;      // 32000*512
    u16* Wp_b    = Wc_b + 524288;        // 512*1024
    u16* ctx_b   = Wp_b + 524288;
    u16* phr_b   = ctx_b + 2097152;      // 2048*1024
    u16* feats_b = phr_b + 2097152;      // 4096*512
    // pm/ps/tlog alias the ctx region (dead after k_feats; k_lse runs later in-stream)
    float* pm    = (float*)ctx_b;                 // 4096*32
    float* ps    = pm + NROWS * NCHUNK;           // 4096*32
    float* tlog  = ps + NROWS * NCHUNK;           // 8192

    k_convert<<<2048, 256, 0, stream>>>(Wo, Wo_b, 16384000);
    k_convert<<<256, 256, 0, stream>>>(Wc, Wc_b, 524288);
    k_convert<<<256, 256, 0, stream>>>(Wp, Wp_b, 524288);
    k_gather<<<2048, 256, 0, stream>>>(hidden, begins, ends, bids, ctx_b, phr_b);
    k_feats<<<dim3(32, 8, 2), 256, 0, stream>>>(ctx_b, phr_b, Wc_b, Wp_b, bc, bp, feats_b);
    k_lse<<<dim3(32, NCHUNK), 256, 0, stream>>>(feats_b, Wo_b, pm, ps);
    k_taglog<<<2048, 256, 0, stream>>>(feats_b, Wo_b, bo, tags, tlog);
    k_final<<<1, 256, 0, stream>>>(pm, ps, tlog, tags, dp, out);
}